// Round 7
// baseline (1744.675 us; speedup 1.0000x reference)
//
#include <hip/hip_runtime.h>
#include <math.h>

typedef unsigned int u32;
typedef unsigned short u16;
typedef short s16x8 __attribute__((ext_vector_type(8)));
typedef float f32x4 __attribute__((ext_vector_type(4)));
typedef u16 u16x4 __attribute__((ext_vector_type(4)));
typedef u16 u16x8 __attribute__((ext_vector_type(8)));

#define B_  16
#define S_  2048
#define D_  1024
#define H_  256
#define SD_ 14
#define C_  6
#define G_  3
#define E_  18

static __device__ __forceinline__ u16 f2bf(float f) {
  u32 x = __builtin_bit_cast(u32, f);
  return (u16)((x + 0x7fffu + ((x >> 16) & 1u)) >> 16);
}

// ---------------- K3: convert features f32->bf16 + column-mean pooling ----------------
__global__ __launch_bounds__(256) void k_convpool(const float* __restrict__ F,
                                                  u16* __restrict__ Fbf,
                                                  float* __restrict__ fsum) {
  const int bb = blockIdx.x >> 5;
  const int sc = blockIdx.x & 31;
  const int t  = threadIdx.x;
  const size_t base = (size_t)(bb * S_ + sc * 64) * D_ + t * 4;
  float s0 = 0.f, s1 = 0.f, s2 = 0.f, s3 = 0.f;
  for (int i = 0; i < 64; ++i) {
    const f32x4 v = *(const f32x4*)(F + base + (size_t)i * D_);
    s0 += v[0]; s1 += v[1]; s2 += v[2]; s3 += v[3];
    u16x4 h;
    h[0] = f2bf(v[0]); h[1] = f2bf(v[1]); h[2] = f2bf(v[2]); h[3] = f2bf(v[3]);
    *(u16x4*)(Fbf + base + (size_t)i * D_) = h;
  }
  const int c = t * 4;
  atomicAdd(&fsum[bb * D_ + c + 0], s0);
  atomicAdd(&fsum[bb * D_ + c + 1], s1);
  atomicAdd(&fsum[bb * D_ + c + 2], s2);
  atomicAdd(&fsum[bb * D_ + c + 3], s3);
}

// ---------------- K3b: pooling only (lean path) ----------------
__global__ __launch_bounds__(256) void k_poolF(const float* __restrict__ F,
                                               float* __restrict__ fsum) {
  const int bb = blockIdx.x >> 5;
  const int sc = blockIdx.x & 31;
  const int t  = threadIdx.x;
  const size_t base = (size_t)(bb * S_ + sc * 64) * D_ + t * 4;
  float s0 = 0.f, s1 = 0.f, s2 = 0.f, s3 = 0.f;
  for (int i = 0; i < 64; ++i) {
    const f32x4 v = *(const f32x4*)(F + base + (size_t)i * D_);
    s0 += v[0]; s1 += v[1]; s2 += v[2]; s3 += v[3];
  }
  const int c = t * 4;
  atomicAdd(&fsum[bb * D_ + c + 0], s0);
  atomicAdd(&fsum[bb * D_ + c + 1], s1);
  atomicAdd(&fsum[bb * D_ + c + 2], s2);
  atomicAdd(&fsum[bb * D_ + c + 3], s3);
}

// ---------------- K1: x_raw column-mean pooling ----------------
__global__ __launch_bounds__(256) void k_xpool(const float* __restrict__ X,
                                               float* __restrict__ xsum) {
  const int b = blockIdx.x;
  const int t = threadIdx.x;
  float ls[SD_];
  #pragma unroll
  for (int c = 0; c < SD_; ++c) ls[c] = 0.f;
  for (int s = t; s < S_; s += 256) {
    const float* row = X + (size_t)(b * S_ + s) * SD_;
    #pragma unroll
    for (int c = 0; c < SD_; ++c) ls[c] += row[c];
  }
  #pragma unroll
  for (int c = 0; c < SD_; ++c) atomicAdd(&xsum[b * SD_ + c], ls[c]);
}

// ---------------- K2: routers + flat weights + expert loads + lb + bias term ----------------
__global__ __launch_bounds__(256) void k_router(const float* __restrict__ fsum,
                                                const float* __restrict__ xsum,
                                                const float* __restrict__ cond_w,
                                                const float* __restrict__ cond_b,
                                                const float* __restrict__ stage_w,
                                                const float* __restrict__ stage_b,
                                                const float* __restrict__ up_b,
                                                float* __restrict__ flatw,
                                                float* __restrict__ biasws,
                                                float* __restrict__ out_tail) {
  __shared__ float s_cl[B_][C_], s_sl[B_][G_];
  __shared__ float s_cw[B_][C_], s_sw[B_][G_];
  __shared__ float s_fw[B_][E_], s_ld[E_];
  const int t = threadIdx.x;
  if (t < B_ * C_) {
    const int b = t / C_, c = t % C_;
    float a = cond_b[c];
    for (int d = 0; d < D_; ++d) a += (fsum[b * D_ + d] * (1.f / S_)) * cond_w[d * C_ + c];
    s_cl[b][c] = a;
  }
  if (t < B_ * G_) {
    const int b = t / G_, g = t % G_;
    float a = stage_b[g];
    for (int sd = 0; sd < SD_; ++sd) a += (xsum[b * SD_ + sd] * (1.f / S_)) * stage_w[sd * G_ + g];
    s_sl[b][g] = a;
  }
  __syncthreads();
  if (t < B_) {
    float m = s_cl[t][0];
    for (int c = 1; c < C_; ++c) m = fmaxf(m, s_cl[t][c]);
    float den = 0.f, ex[C_];
    for (int c = 0; c < C_; ++c) { ex[c] = expf(s_cl[t][c] - m); den += ex[c]; }
    for (int c = 0; c < C_; ++c) s_cw[t][c] = ex[c] / den;
    float m2 = s_sl[t][0];
    for (int g = 1; g < G_; ++g) m2 = fmaxf(m2, s_sl[t][g]);
    float den2 = 0.f, ex2[G_];
    for (int g = 0; g < G_; ++g) { ex2[g] = expf(s_sl[t][g] - m2); den2 += ex2[g]; }
    for (int g = 0; g < G_; ++g) s_sw[t][g] = ex2[g] / den2;
    for (int c = 0; c < C_; ++c)
      for (int g = 0; g < G_; ++g) s_fw[t][c * G_ + g] = s_cw[t][c] * s_sw[t][g];
  }
  __syncthreads();
  if (t < B_ * C_) out_tail[t] = s_cw[t / C_][t % C_];
  if (t < B_ * G_) out_tail[B_ * C_ + t] = s_sw[t / G_][t % G_];
  for (int i = t; i < B_ * E_; i += 256) flatw[i] = s_fw[i / E_][i % E_];
  if (t < E_) {
    float a = 0.f;
    for (int b = 0; b < B_; ++b) a += s_fw[b][t];
    s_ld[t] = a / (float)B_;
    out_tail[B_ * C_ + B_ * G_ + t] = s_ld[t];
  }
  __syncthreads();
  if (t == 0) {
    float a = 0.f;
    for (int e = 0; e < E_; ++e) a += s_ld[e] * s_ld[e];
    out_tail[B_ * C_ + B_ * G_ + E_] = (float)E_ * a * 0.01f;
  }
  for (int i = t; i < B_ * D_; i += 256) {
    const int b = i >> 10, d = i & 1023;
    float a = 0.f;
    #pragma unroll
    for (int e = 0; e < E_; ++e) a += s_fw[b][e] * up_b[e * D_ + d];
    biasws[i] = a;
  }
}

// ---------------- K4: fragmentizer ----------------
// src: [E][K][N] f32 -> dst frag-linear bf16 [e][kb=K/32][cb=N/16][lane=64][8]:
//   dst = src[e][kb*32 + (lane>>4)*8 + j][cb*16 + (lane&15)]
__global__ __launch_bounds__(256) void k_frag(const float* __restrict__ src,
                                              u16* __restrict__ dst, int K, int N) {
  const int kgrp = K >> 7;
  const int ncb = N >> 4;
  const int bid = blockIdx.x;
  const int kbg = bid % kgrp;
  const int cb  = (bid / kgrp) % ncb;
  const int e   = bid / (kgrp * ncb);
  __shared__ float tile[128][17];
  const int t = threadIdx.x;
  #pragma unroll
  for (int it = 0; it < 8; ++it) {
    const int i = it * 256 + t;
    const int row = i >> 4, col = i & 15;
    tile[row][col] = src[((size_t)e * K + kbg * 128 + row) * N + cb * 16 + col];
  }
  __syncthreads();
  const int lane = t & 63, kbq = t >> 6;
  const int l15 = lane & 15, lhi = lane >> 4;
  const int kb = kbg * 4 + kbq;
  u16x8 h;
  #pragma unroll
  for (int j = 0; j < 8; ++j) h[j] = f2bf(tile[kbq * 32 + lhi * 8 + j][l15]);
  *(u16x8*)(dst + ((((size_t)e * (K >> 5) + kb) * ncb + cb) * 64 + lane) * 8) = h;
}

#define MFMA_BF16 __builtin_amdgcn_mfma_f32_16x16x32_bf16

// fast gelu (tanh form via exp2)
static __device__ __forceinline__ float gelu_f(float x) {
  float y2 = 2.302208f * x * (1.f + 0.044715f * x * x);
  y2 = fminf(fmaxf(y2, -30.f), 30.f);
  const float p = __builtin_exp2f(y2);
  return x * p / (p + 1.f);
}

// ---------------- K5: fused MoE main kernel (v7 = v5 + depth-8 down-B) ----------------
// BM=32, 512 thr / 8 waves, 2 waves/SIMD (reg budget 256/wave: acc 64 + ~150
// VGPR, verified no-spill in v5 at depth 4 with VGPR=116). v7 deepens the
// down-B rolling prefetch 4->8 (+32 regs): coverage ~320 wall-cycles > ~200cyc
// L2 latency, the stall v5's MfmaUtil=22.6% pointed at.
template<int LEAN>
__global__ __launch_bounds__(512, 2) void k_moe(const u16* __restrict__ Fbf,
                                                const float* __restrict__ Ff32,
                                                const u16* __restrict__ dwF,   // [e][32][16][64][8]
                                                const u16* __restrict__ uwF,   // [e][8][64][64][8]
                                                const float* __restrict__ down_b,
                                                const float* __restrict__ flatw,
                                                const float* __restrict__ biasws,
                                                float* __restrict__ out) {
  __shared__ u16 Fb[32 * 1024];     // 64 KiB, row stride 2048B, XOR-swizzled 16B slots
  __shared__ u16 Hb[2][32 * 256];   // 2 x 16 KiB

  const int tile = blockIdx.x;
  const int r0 = tile * 32;
  const int b = r0 >> 11;
  const int t = threadIdx.x;
  const int w = t >> 6;
  const int l = t & 63;
  const int l15 = l & 15;
  const int lhi = l >> 4;
  const int sw7 = (l & 7) << 4;

  // ---- stage F tile ----
  #pragma unroll
  for (int i = 0; i < 8; ++i) {
    const int slot = i * 512 + t;
    const int row = slot >> 7;
    const int isl = slot & 127;
    char* dst = (char*)Fb + row * 2048 + ((isl * 16) ^ ((row & 7) << 4));
    if constexpr (!LEAN) {
      *(u16x8*)dst = *(const u16x8*)(Fbf + (size_t)(r0 + row) * D_ + isl * 8);
    } else {
      const float* src = Ff32 + (size_t)(r0 + row) * D_ + isl * 8;
      const f32x4 v0 = *(const f32x4*)src;
      const f32x4 v1 = *(const f32x4*)(src + 4);
      u16x8 h;
      h[0] = f2bf(v0[0]); h[1] = f2bf(v0[1]); h[2] = f2bf(v0[2]); h[3] = f2bf(v0[3]);
      h[4] = f2bf(v1[0]); h[5] = f2bf(v1[1]); h[6] = f2bf(v1[2]); h[7] = f2bf(v1[3]);
      *(u16x8*)dst = h;
    }
  }

  // down-B frag base for this wave/lane: [e][kk][cb][lane][8], wave covers cb=2w,2w+1
  const u16* dB = dwF + ((size_t)(2 * w) * 64 + l) * 8;   // + (e*32+kk)*16*512
  const u16* uB = uwF + ((size_t)(8 * w) * 64 + l) * 8;   // + (e*8+ks)*64*512, frag fc: +fc*512

  // preload expert-0 down-B, depth 8 (kk=0..7), 2 frags each
  s16x8 pb[8][2];
  #pragma unroll
  for (int p = 0; p < 8; ++p) {
    pb[p][0] = *(const s16x8*)(dB + (size_t)p * 16 * 512);
    pb[p][1] = *(const s16x8*)(dB + (size_t)p * 16 * 512 + 512);
  }

  f32x4 acc[2][8];
  #pragma unroll
  for (int i = 0; i < 2; ++i)
    #pragma unroll
    for (int j = 0; j < 8; ++j)
      acc[i][j] = f32x4{0.f, 0.f, 0.f, 0.f};

  __syncthreads();

  const float* fwb = flatw + b * E_;

  #pragma unroll 1
  for (int e = 0; e < E_; ++e) {
    char* hb = (char*)Hb[e & 1];
    const u16* dBe = dB + (size_t)e * 32 * 16 * 512;
    // ---- DOWN: h[32 x 32cols/wave] ----
    f32x4 hacc[2][2];
    #pragma unroll
    for (int fr = 0; fr < 2; ++fr) {
      hacc[fr][0] = f32x4{0.f, 0.f, 0.f, 0.f};
      hacc[fr][1] = f32x4{0.f, 0.f, 0.f, 0.f};
    }
    s16x8 areg[2][2];
    #pragma unroll
    for (int fr = 0; fr < 2; ++fr)
      areg[0][fr] = *(const s16x8*)((const char*)Fb + (l15 + fr * 16) * 2048 + ((lhi * 16) ^ sw7));
    #pragma unroll
    for (int kk = 0; kk < 32; ++kk) {
      const int cur = kk & 1, nxt = cur ^ 1;
      if (kk < 31) {
        const int kb = (kk + 1) * 64;
        #pragma unroll
        for (int fr = 0; fr < 2; ++fr)
          areg[nxt][fr] = *(const s16x8*)((const char*)Fb + (l15 + fr * 16) * 2048 + ((kb + lhi * 16) ^ sw7));
      }
      const s16x8 b0 = pb[kk & 7][0];
      const s16x8 b1 = pb[kk & 7][1];
      if (kk < 24) {
        pb[kk & 7][0] = *(const s16x8*)(dBe + (size_t)(kk + 8) * 16 * 512);
        pb[kk & 7][1] = *(const s16x8*)(dBe + (size_t)(kk + 8) * 16 * 512 + 512);
      }
      #pragma unroll
      for (int fr = 0; fr < 2; ++fr) {
        hacc[fr][0] = MFMA_BF16(areg[cur][fr], b0, hacc[fr][0], 0, 0, 0);
        hacc[fr][1] = MFMA_BF16(areg[cur][fr], b1, hacc[fr][1], 0, 0, 0);
      }
    }

    // ---- issue up-B(ks=0) + next-expert pb BEFORE the gelu stores (more cover) ----
    const u16* uBe = uB + (size_t)e * 8 * 64 * 512;
    s16x8 ub[2][8];
    #pragma unroll
    for (int fc = 0; fc < 8; ++fc)
      ub[0][fc] = *(const s16x8*)(uBe + (size_t)fc * 512);

    if (e + 1 < E_) {
      const u16* dBn = dB + (size_t)(e + 1) * 32 * 16 * 512;
      #pragma unroll
      for (int p = 0; p < 8; ++p) {
        pb[p][0] = *(const s16x8*)(dBn + (size_t)p * 16 * 512);
        pb[p][1] = *(const s16x8*)(dBn + (size_t)p * 16 * 512 + 512);
      }
    }

    const float wbe = fwb[e];
    #pragma unroll
    for (int fc = 0; fc < 2; ++fc) {
      const int hc = w * 32 + fc * 16 + l15;
      const float dbv = down_b[e * H_ + hc];
      #pragma unroll
      for (int fr = 0; fr < 2; ++fr) {
        #pragma unroll
        for (int i = 0; i < 4; ++i) {
          const int row = fr * 16 + lhi * 4 + i;
          const float x = hacc[fr][fc][i] + dbv;
          *(u16*)(hb + row * 512 + ((hc * 2) ^ ((row & 7) << 4))) = f2bf(gelu_f(x) * wbe);
        }
      }
    }

    // single barrier/expert: publishes Hb[e&1]; up(e) reads it while gelu(e+1)
    // writes the OTHER buffer; up(e+1) gated by barrier(e+1).
    __syncthreads();

    // ---- UP: acc[32 x 128cols/wave] += Hb @ uw[e] ----
    s16x8 ua[2][2];
    #pragma unroll
    for (int fr = 0; fr < 2; ++fr)
      ua[0][fr] = *(const s16x8*)(hb + (l15 + fr * 16) * 512 + ((lhi * 16) ^ sw7));
    #pragma unroll
    for (int ks = 0; ks < 8; ++ks) {
      const int cur = ks & 1, nxt = cur ^ 1;
      if (ks < 7) {
        #pragma unroll
        for (int fc = 0; fc < 8; ++fc)
          ub[nxt][fc] = *(const s16x8*)(uBe + ((size_t)(ks + 1) * 64 + fc) * 512);
        const int kb = (ks + 1) * 64;
        #pragma unroll
        for (int fr = 0; fr < 2; ++fr)
          ua[nxt][fr] = *(const s16x8*)(hb + (l15 + fr * 16) * 512 + ((kb + lhi * 16) ^ sw7));
      }
      #pragma unroll
      for (int fc = 0; fc < 8; ++fc) {
        #pragma unroll
        for (int fr = 0; fr < 2; ++fr)
          acc[fr][fc] = MFMA_BF16(ua[cur][fr], ub[cur][fc], acc[fr][fc], 0, 0, 0);
      }
    }
  }

  // ---- epilogue: residual + bias + store ----
  const float* bias = biasws + b * D_;
  #pragma unroll
  for (int fc = 0; fc < 8; ++fc) {
    const int col = w * 128 + fc * 16 + l15;
    const float bv = bias[col];
    #pragma unroll
    for (int fr = 0; fr < 2; ++fr) {
      #pragma unroll
      for (int i = 0; i < 4; ++i) {
        const int row = fr * 16 + lhi * 4 + i;
        const size_t idx = (size_t)(r0 + row) * D_ + col;
        out[idx] = acc[fr][fc][i] + Ff32[idx] + bv;
      }
    }
  }
}

extern "C" void kernel_launch(void* const* d_in, const int* in_sizes, int n_in,
                              void* d_out, int out_size, void* d_ws, size_t ws_size,
                              hipStream_t stream) {
  const float* F  = (const float*)d_in[0];
  const float* X  = (const float*)d_in[1];
  const float* dw = (const float*)d_in[2];
  const float* db = (const float*)d_in[3];
  const float* uw = (const float*)d_in[4];
  const float* ub = (const float*)d_in[5];
  const float* cw = (const float*)d_in[6];
  const float* cb = (const float*)d_in[7];
  const float* sw = (const float*)d_in[8];
  const float* sb = (const float*)d_in[9];
  float* out = (float*)d_out;

  char* ws = (char*)d_ws;
  float* fsum  = (float*)ws;                 // B*D
  float* xsum  = fsum + B_ * D_;             // B*SD
  float* flatw = xsum + B_ * SD_;            // B*E
  float* biasws = flatw + B_ * E_;           // B*D
  size_t off = (size_t)(B_ * D_ + B_ * SD_ + B_ * E_ + B_ * D_) * 4;
  off = (off + 255) & ~(size_t)255;
  u16* dwF = (u16*)(ws + off); off += (size_t)E_ * H_ * D_ * 2;
  u16* uwF = (u16*)(ws + off); off += (size_t)E_ * D_ * H_ * 2;
  const size_t need_lean = off;
  u16* Fbf = (u16*)(ws + off); off += (size_t)B_ * S_ * D_ * 2;
  const size_t need_full = off;

  if (ws_size < need_lean) return;
  const bool lean = ws_size < need_full;

  hipMemsetAsync(d_ws, 0, (size_t)(B_ * D_ + B_ * SD_) * sizeof(float), stream);
  k_frag<<<E_ * (H_ / 16) * (D_ / 128), 256, 0, stream>>>(dw, dwF, D_, H_);
  k_frag<<<E_ * (D_ / 16) * (H_ / 128), 256, 0, stream>>>(uw, uwF, H_, D_);
  if (!lean) {
    k_convpool<<<512, 256, 0, stream>>>(F, Fbf, fsum);
  } else {
    k_poolF<<<512, 256, 0, stream>>>(F, fsum);
  }
  k_xpool<<<B_, 256, 0, stream>>>(X, xsum);
  k_router<<<1, 256, 0, stream>>>(fsum, xsum, cw, cb, sw, sb, ub, flatw, biasws,
                                  out + (size_t)B_ * S_ * D_);
  if (!lean) {
    k_moe<0><<<1024, 512, 0, stream>>>(Fbf, F, dwF, uwF, db, flatw, biasws, out);
  } else {
    k_moe<1><<<1024, 512, 0, stream>>>(nullptr, F, dwF, uwF, db, flatw, biasws, out);
  }
}

// Round 8
// 1436.146 us; speedup vs baseline: 1.2148x; 1.2148x over previous
//
#include <hip/hip_runtime.h>
#include <math.h>

typedef unsigned int u32;
typedef unsigned short u16;
typedef short s16x8 __attribute__((ext_vector_type(8)));
typedef float f32x4 __attribute__((ext_vector_type(4)));
typedef u16 u16x4 __attribute__((ext_vector_type(4)));
typedef u16 u16x8 __attribute__((ext_vector_type(8)));

#define B_  16
#define S_  2048
#define D_  1024
#define H_  256
#define SD_ 14
#define C_  6
#define G_  3
#define E_  18

static __device__ __forceinline__ u16 f2bf(float f) {
  u32 x = __builtin_bit_cast(u32, f);
  return (u16)((x + 0x7fffu + ((x >> 16) & 1u)) >> 16);
}

// ---------------- K3: convert features f32->bf16 + column-mean pooling ----------------
__global__ __launch_bounds__(256) void k_convpool(const float* __restrict__ F,
                                                  u16* __restrict__ Fbf,
                                                  float* __restrict__ fsum) {
  const int bb = blockIdx.x >> 5;
  const int sc = blockIdx.x & 31;
  const int t  = threadIdx.x;
  const size_t base = (size_t)(bb * S_ + sc * 64) * D_ + t * 4;
  float s0 = 0.f, s1 = 0.f, s2 = 0.f, s3 = 0.f;
  for (int i = 0; i < 64; ++i) {
    const f32x4 v = *(const f32x4*)(F + base + (size_t)i * D_);
    s0 += v[0]; s1 += v[1]; s2 += v[2]; s3 += v[3];
    u16x4 h;
    h[0] = f2bf(v[0]); h[1] = f2bf(v[1]); h[2] = f2bf(v[2]); h[3] = f2bf(v[3]);
    *(u16x4*)(Fbf + base + (size_t)i * D_) = h;
  }
  const int c = t * 4;
  atomicAdd(&fsum[bb * D_ + c + 0], s0);
  atomicAdd(&fsum[bb * D_ + c + 1], s1);
  atomicAdd(&fsum[bb * D_ + c + 2], s2);
  atomicAdd(&fsum[bb * D_ + c + 3], s3);
}

// ---------------- K3b: pooling only (lean path) ----------------
__global__ __launch_bounds__(256) void k_poolF(const float* __restrict__ F,
                                               float* __restrict__ fsum) {
  const int bb = blockIdx.x >> 5;
  const int sc = blockIdx.x & 31;
  const int t  = threadIdx.x;
  const size_t base = (size_t)(bb * S_ + sc * 64) * D_ + t * 4;
  float s0 = 0.f, s1 = 0.f, s2 = 0.f, s3 = 0.f;
  for (int i = 0; i < 64; ++i) {
    const f32x4 v = *(const f32x4*)(F + base + (size_t)i * D_);
    s0 += v[0]; s1 += v[1]; s2 += v[2]; s3 += v[3];
  }
  const int c = t * 4;
  atomicAdd(&fsum[bb * D_ + c + 0], s0);
  atomicAdd(&fsum[bb * D_ + c + 1], s1);
  atomicAdd(&fsum[bb * D_ + c + 2], s2);
  atomicAdd(&fsum[bb * D_ + c + 3], s3);
}

// ---------------- K1: x_raw column-mean pooling ----------------
__global__ __launch_bounds__(256) void k_xpool(const float* __restrict__ X,
                                               float* __restrict__ xsum) {
  const int b = blockIdx.x;
  const int t = threadIdx.x;
  float ls[SD_];
  #pragma unroll
  for (int c = 0; c < SD_; ++c) ls[c] = 0.f;
  for (int s = t; s < S_; s += 256) {
    const float* row = X + (size_t)(b * S_ + s) * SD_;
    #pragma unroll
    for (int c = 0; c < SD_; ++c) ls[c] += row[c];
  }
  #pragma unroll
  for (int c = 0; c < SD_; ++c) atomicAdd(&xsum[b * SD_ + c], ls[c]);
}

// ---------------- K2: routers + flat weights + expert loads + lb + bias term ----------------
__global__ __launch_bounds__(256) void k_router(const float* __restrict__ fsum,
                                                const float* __restrict__ xsum,
                                                const float* __restrict__ cond_w,
                                                const float* __restrict__ cond_b,
                                                const float* __restrict__ stage_w,
                                                const float* __restrict__ stage_b,
                                                const float* __restrict__ up_b,
                                                float* __restrict__ flatw,
                                                float* __restrict__ biasws,
                                                float* __restrict__ out_tail) {
  __shared__ float s_cl[B_][C_], s_sl[B_][G_];
  __shared__ float s_cw[B_][C_], s_sw[B_][G_];
  __shared__ float s_fw[B_][E_], s_ld[E_];
  const int t = threadIdx.x;
  if (t < B_ * C_) {
    const int b = t / C_, c = t % C_;
    float a = cond_b[c];
    for (int d = 0; d < D_; ++d) a += (fsum[b * D_ + d] * (1.f / S_)) * cond_w[d * C_ + c];
    s_cl[b][c] = a;
  }
  if (t < B_ * G_) {
    const int b = t / G_, g = t % G_;
    float a = stage_b[g];
    for (int sd = 0; sd < SD_; ++sd) a += (xsum[b * SD_ + sd] * (1.f / S_)) * stage_w[sd * G_ + g];
    s_sl[b][g] = a;
  }
  __syncthreads();
  if (t < B_) {
    float m = s_cl[t][0];
    for (int c = 1; c < C_; ++c) m = fmaxf(m, s_cl[t][c]);
    float den = 0.f, ex[C_];
    for (int c = 0; c < C_; ++c) { ex[c] = expf(s_cl[t][c] - m); den += ex[c]; }
    for (int c = 0; c < C_; ++c) s_cw[t][c] = ex[c] / den;
    float m2 = s_sl[t][0];
    for (int g = 1; g < G_; ++g) m2 = fmaxf(m2, s_sl[t][g]);
    float den2 = 0.f, ex2[G_];
    for (int g = 0; g < G_; ++g) { ex2[g] = expf(s_sl[t][g] - m2); den2 += ex2[g]; }
    for (int g = 0; g < G_; ++g) s_sw[t][g] = ex2[g] / den2;
    for (int c = 0; c < C_; ++c)
      for (int g = 0; g < G_; ++g) s_fw[t][c * G_ + g] = s_cw[t][c] * s_sw[t][g];
  }
  __syncthreads();
  if (t < B_ * C_) out_tail[t] = s_cw[t / C_][t % C_];
  if (t < B_ * G_) out_tail[B_ * C_ + t] = s_sw[t / G_][t % G_];
  for (int i = t; i < B_ * E_; i += 256) flatw[i] = s_fw[i / E_][i % E_];
  if (t < E_) {
    float a = 0.f;
    for (int b = 0; b < B_; ++b) a += s_fw[b][t];
    s_ld[t] = a / (float)B_;
    out_tail[B_ * C_ + B_ * G_ + t] = s_ld[t];
  }
  __syncthreads();
  if (t == 0) {
    float a = 0.f;
    for (int e = 0; e < E_; ++e) a += s_ld[e] * s_ld[e];
    out_tail[B_ * C_ + B_ * G_ + E_] = (float)E_ * a * 0.01f;
  }
  for (int i = t; i < B_ * D_; i += 256) {
    const int b = i >> 10, d = i & 1023;
    float a = 0.f;
    #pragma unroll
    for (int e = 0; e < E_; ++e) a += s_fw[b][e] * up_b[e * D_ + d];
    biasws[i] = a;
  }
}

// ---------------- K4: fragmentizer ----------------
// src: [E][K][N] f32 -> dst frag-linear bf16 [e][kb=K/32][cb=N/16][lane=64][8]:
//   dst = src[e][kb*32 + (lane>>4)*8 + j][cb*16 + (lane&15)]
__global__ __launch_bounds__(256) void k_frag(const float* __restrict__ src,
                                              u16* __restrict__ dst, int K, int N) {
  const int kgrp = K >> 7;
  const int ncb = N >> 4;
  const int bid = blockIdx.x;
  const int kbg = bid % kgrp;
  const int cb  = (bid / kgrp) % ncb;
  const int e   = bid / (kgrp * ncb);
  __shared__ float tile[128][17];
  const int t = threadIdx.x;
  #pragma unroll
  for (int it = 0; it < 8; ++it) {
    const int i = it * 256 + t;
    const int row = i >> 4, col = i & 15;
    tile[row][col] = src[((size_t)e * K + kbg * 128 + row) * N + cb * 16 + col];
  }
  __syncthreads();
  const int lane = t & 63, kbq = t >> 6;
  const int l15 = lane & 15, lhi = lane >> 4;
  const int kb = kbg * 4 + kbq;
  u16x8 h;
  #pragma unroll
  for (int j = 0; j < 8; ++j) h[j] = f2bf(tile[kbq * 32 + lhi * 8 + j][l15]);
  *(u16x8*)(dst + ((((size_t)e * (K >> 5) + kb) * ncb + cb) * 64 + lane) * 8) = h;
}

#define MFMA_BF16 __builtin_amdgcn_mfma_f32_16x16x32_bf16

// fast gelu (tanh form via exp2)
static __device__ __forceinline__ float gelu_f(float x) {
  float y2 = 2.302208f * x * (1.f + 0.044715f * x * x);
  y2 = fminf(fmaxf(y2, -30.f), 30.f);
  const float p = __builtin_exp2f(y2);
  return x * p / (p + 1.f);
}

// async global -> LDS, 16B per lane; LDS dest = wave-uniform base + lane*16.
#define STAGE(g, p)                                                             \
  __builtin_amdgcn_global_load_lds(                                             \
      (const __attribute__((address_space(1))) void*)(g),                       \
      (__attribute__((address_space(3))) void*)(p), 16, 0, 0)

#define WAITV(N) asm volatile("s_waitcnt vmcnt(" #N ")" ::: "memory")

// ---------------- K5: fused MoE main kernel (v8 = v5 + LDS ring for down-B) ----------------
// BM=32, 512 thr / 8 waves, 2 waves/SIMD. HW-calibrated reg budget: 256/wave
// TOTAL (VGPR+AGPR; per-SIMD pool = 512, rounds 3/6/7 evidence). v8 moves the
// down-B prefetch out of registers into a wave-PRIVATE LDS ring (4 slots x 2
// frags x 1KB/wave = 64KB) fed by global_load_lds (0 VGPR) and drained with
// counted vmcnt — no barriers in the down loop, so no cross-wave races.
// Frees 32 VGPRs vs v5. LDS = 64(F) + 32(Hb dbuf) + 64(ring) = 160 KiB exact.
template<int LEAN>
__global__ __launch_bounds__(512, 2) void k_moe(const u16* __restrict__ Fbf,
                                                const float* __restrict__ Ff32,
                                                const u16* __restrict__ dwF,   // [e][32][16][64][8]
                                                const u16* __restrict__ uwF,   // [e][8][64][64][8]
                                                const float* __restrict__ down_b,
                                                const float* __restrict__ flatw,
                                                const float* __restrict__ biasws,
                                                float* __restrict__ out) {
  __shared__ u16 Fb[32 * 1024];       // 64 KiB
  __shared__ u16 Hb[2][32 * 256];     // 2 x 16 KiB
  __shared__ u16 Wr[8][4][2][512];    // 64 KiB: per-wave ring, 4 slots x 2 frags x 1KB

  const int tile = blockIdx.x;
  const int r0 = tile * 32;
  const int b = r0 >> 11;
  const int t = threadIdx.x;
  const int w = t >> 6;
  const int l = t & 63;
  const int l15 = l & 15;
  const int lhi = l >> 4;
  const int sw7 = (l & 7) << 4;

  // ---- stage F tile ----
  #pragma unroll
  for (int i = 0; i < 8; ++i) {
    const int slot = i * 512 + t;
    const int row = slot >> 7;
    const int isl = slot & 127;
    char* dst = (char*)Fb + row * 2048 + ((isl * 16) ^ ((row & 7) << 4));
    if constexpr (!LEAN) {
      *(u16x8*)dst = *(const u16x8*)(Fbf + (size_t)(r0 + row) * D_ + isl * 8);
    } else {
      const float* src = Ff32 + (size_t)(r0 + row) * D_ + isl * 8;
      const f32x4 v0 = *(const f32x4*)src;
      const f32x4 v1 = *(const f32x4*)(src + 4);
      u16x8 h;
      h[0] = f2bf(v0[0]); h[1] = f2bf(v0[1]); h[2] = f2bf(v0[2]); h[3] = f2bf(v0[3]);
      h[4] = f2bf(v1[0]); h[5] = f2bf(v1[1]); h[6] = f2bf(v1[2]); h[7] = f2bf(v1[3]);
      *(u16x8*)dst = h;
    }
  }

  // per-lane frag bases (frag-linear layout: lane l's 16B at +l*8 u16)
  const u16* dB = dwF + ((size_t)(2 * w) * 64 + l) * 8;   // + (e*32+kk)*16*512 (+512 for cb+1)
  const u16* uB = uwF + ((size_t)(8 * w) * 64 + l) * 8;   // + (e*8+ks)*64*512 (+fc*512)

  // ring prologue for e=0: slots 0..3 (drained by the syncthreads below — once)
  #pragma unroll
  for (int p = 0; p < 4; ++p) {
    STAGE(dB + (size_t)p * 16 * 512,       &Wr[w][p][0][0]);
    STAGE(dB + (size_t)p * 16 * 512 + 512, &Wr[w][p][1][0]);
  }

  f32x4 acc[2][8];
  #pragma unroll
  for (int i = 0; i < 2; ++i)
    #pragma unroll
    for (int j = 0; j < 8; ++j)
      acc[i][j] = f32x4{0.f, 0.f, 0.f, 0.f};

  __syncthreads();

  const float* fwb = flatw + b * E_;

  #pragma unroll 1
  for (int e = 0; e < E_; ++e) {
    char* hb = (char*)Hb[e & 1];
    const u16* dBe = dB + (size_t)e * 32 * 16 * 512;

    // ---- DOWN: h[32 x 32cols/wave], B-frags via wave-private LDS ring ----
    f32x4 hacc[2][2];
    #pragma unroll
    for (int fr = 0; fr < 2; ++fr) {
      hacc[fr][0] = f32x4{0.f, 0.f, 0.f, 0.f};
      hacc[fr][1] = f32x4{0.f, 0.f, 0.f, 0.f};
    }
    s16x8 areg[2][2], breg[2][2];
    #pragma unroll
    for (int fr = 0; fr < 2; ++fr)
      areg[0][fr] = *(const s16x8*)((const char*)Fb + (l15 + fr * 16) * 2048 + ((lhi * 16) ^ sw7));
    // slot 0 ready when <=6 of the 8 prologue stages remain
    WAITV(6);
    breg[0][0] = *(const s16x8*)(&Wr[w][0][0][0] + l * 8);
    breg[0][1] = *(const s16x8*)(&Wr[w][0][1][0] + l * 8);

    #pragma unroll
    for (int kk = 0; kk < 32; ++kk) {
      const int cur = kk & 1, nxt = cur ^ 1;
      if (kk < 31) {
        const int kb = (kk + 1) * 64;
        #pragma unroll
        for (int fr = 0; fr < 2; ++fr)
          areg[nxt][fr] = *(const s16x8*)((const char*)Fb + (l15 + fr * 16) * 2048 + ((kb + lhi * 16) ^ sw7));
      }
      if (kk < 28) {
        const int sl = (kk + 4) & 3;
        STAGE(dBe + (size_t)(kk + 4) * 16 * 512,       &Wr[w][sl][0][0]);
        STAGE(dBe + (size_t)(kk + 4) * 16 * 512 + 512, &Wr[w][sl][1][0]);
      }
      // wait for slot kk+1 (in-order vmcnt retirement; foreign loads only add slack)
      if (kk <= 27) { WAITV(6); }
      else if (kk == 28) { WAITV(4); }
      else if (kk == 29) { WAITV(2); }
      else if (kk == 30) { WAITV(0); }
      if (kk < 31) {
        const int sl = (kk + 1) & 3;
        breg[nxt][0] = *(const s16x8*)(&Wr[w][sl][0][0] + l * 8);
        breg[nxt][1] = *(const s16x8*)(&Wr[w][sl][1][0] + l * 8);
      }
      #pragma unroll
      for (int fr = 0; fr < 2; ++fr) {
        hacc[fr][0] = MFMA_BF16(areg[cur][fr], breg[cur][0], hacc[fr][0], 0, 0, 0);
        hacc[fr][1] = MFMA_BF16(areg[cur][fr], breg[cur][1], hacc[fr][1], 0, 0, 0);
      }
    }

    // ring reads fully retired before any overwrite of slots 0..3
    asm volatile("s_waitcnt lgkmcnt(0)" ::: "memory");

    // up-B(ks=0) register loads (needed soonest)
    const u16* uBe = uB + (size_t)e * 8 * 64 * 512;
    s16x8 ub[2][8];
    #pragma unroll
    for (int fc = 0; fc < 8; ++fc)
      ub[0][fc] = *(const s16x8*)(uBe + (size_t)fc * 512);

    // ---- gelu + routing-scale -> Hb[e&1] ----
    const float wbe = fwb[e];
    #pragma unroll
    for (int fc = 0; fc < 2; ++fc) {
      const int hc = w * 32 + fc * 16 + l15;
      const float dbv = down_b[e * H_ + hc];
      #pragma unroll
      for (int fr = 0; fr < 2; ++fr) {
        #pragma unroll
        for (int i = 0; i < 4; ++i) {
          const int row = fr * 16 + lhi * 4 + i;
          const float x = hacc[fr][fc][i] + dbv;
          *(u16*)(hb + row * 512 + ((hc * 2) ^ ((row & 7) << 4))) = f2bf(gelu_f(x) * wbe);
        }
      }
    }

    // single barrier/expert: publishes Hb[e&1]
    __syncthreads();

    // ring prologue for e+1 AFTER the barrier (so the compiler's pre-barrier
    // vmcnt(0) drain doesn't serialize it; overlaps the whole up phase)
    if (e + 1 < E_) {
      const u16* dBn = dB + (size_t)(e + 1) * 32 * 16 * 512;
      #pragma unroll
      for (int p = 0; p < 4; ++p) {
        STAGE(dBn + (size_t)p * 16 * 512,       &Wr[w][p][0][0]);
        STAGE(dBn + (size_t)p * 16 * 512 + 512, &Wr[w][p][1][0]);
      }
    }

    // ---- UP: acc[32 x 128cols/wave] += Hb @ uw[e] ----
    s16x8 ua[2][2];
    #pragma unroll
    for (int fr = 0; fr < 2; ++fr)
      ua[0][fr] = *(const s16x8*)(hb + (l15 + fr * 16) * 512 + ((lhi * 16) ^ sw7));
    #pragma unroll
    for (int ks = 0; ks < 8; ++ks) {
      const int cur = ks & 1, nxt = cur ^ 1;
      if (ks < 7) {
        #pragma unroll
        for (int fc = 0; fc < 8; ++fc)
          ub[nxt][fc] = *(const s16x8*)(uBe + ((size_t)(ks + 1) * 64 + fc) * 512);
        const int kb = (ks + 1) * 64;
        #pragma unroll
        for (int fr = 0; fr < 2; ++fr)
          ua[nxt][fr] = *(const s16x8*)(hb + (l15 + fr * 16) * 512 + ((kb + lhi * 16) ^ sw7));
      }
      #pragma unroll
      for (int fc = 0; fc < 8; ++fc) {
        #pragma unroll
        for (int fr = 0; fr < 2; ++fr)
          acc[fr][fc] = MFMA_BF16(ua[cur][fr], ub[cur][fc], acc[fr][fc], 0, 0, 0);
      }
    }
  }

  // ---- epilogue: residual + bias + store ----
  const float* bias = biasws + b * D_;
  #pragma unroll
  for (int fc = 0; fc < 8; ++fc) {
    const int col = w * 128 + fc * 16 + l15;
    const float bv = bias[col];
    #pragma unroll
    for (int fr = 0; fr < 2; ++fr) {
      #pragma unroll
      for (int i = 0; i < 4; ++i) {
        const int row = fr * 16 + lhi * 4 + i;
        const size_t idx = (size_t)(r0 + row) * D_ + col;
        out[idx] = acc[fr][fc][i] + Ff32[idx] + bv;
      }
    }
  }
}

extern "C" void kernel_launch(void* const* d_in, const int* in_sizes, int n_in,
                              void* d_out, int out_size, void* d_ws, size_t ws_size,
                              hipStream_t stream) {
  const float* F  = (const float*)d_in[0];
  const float* X  = (const float*)d_in[1];
  const float* dw = (const float*)d_in[2];
  const float* db = (const float*)d_in[3];
  const float* uw = (const float*)d_in[4];
  const float* ub = (const float*)d_in[5];
  const float* cw = (const float*)d_in[6];
  const float* cb = (const float*)d_in[7];
  const float* sw = (const float*)d_in[8];
  const float* sb = (const float*)d_in[9];
  float* out = (float*)d_out;

  char* ws = (char*)d_ws;
  float* fsum  = (float*)ws;                 // B*D
  float* xsum  = fsum + B_ * D_;             // B*SD
  float* flatw = xsum + B_ * SD_;            // B*E
  float* biasws = flatw + B_ * E_;           // B*D
  size_t off = (size_t)(B_ * D_ + B_ * SD_ + B_ * E_ + B_ * D_) * 4;
  off = (off + 255) & ~(size_t)255;
  u16* dwF = (u16*)(ws + off); off += (size_t)E_ * H_ * D_ * 2;
  u16* uwF = (u16*)(ws + off); off += (size_t)E_ * D_ * H_ * 2;
  const size_t need_lean = off;
  u16* Fbf = (u16*)(ws + off); off += (size_t)B_ * S_ * D_ * 2;
  const size_t need_full = off;

  if (ws_size < need_lean) return;
  const bool lean = ws_size < need_full;

  hipMemsetAsync(d_ws, 0, (size_t)(B_ * D_ + B_ * SD_) * sizeof(float), stream);
  k_frag<<<E_ * (H_ / 16) * (D_ / 128), 256, 0, stream>>>(dw, dwF, D_, H_);
  k_frag<<<E_ * (D_ / 16) * (H_ / 128), 256, 0, stream>>>(uw, uwF, H_, D_);
  if (!lean) {
    k_convpool<<<512, 256, 0, stream>>>(F, Fbf, fsum);
  } else {
    k_poolF<<<512, 256, 0, stream>>>(F, fsum);
  }
  k_xpool<<<B_, 256, 0, stream>>>(X, xsum);
  k_router<<<1, 256, 0, stream>>>(fsum, xsum, cw, cb, sw, sb, ub, flatw, biasws,
                                  out + (size_t)B_ * S_ * D_);
  if (!lean) {
    k_moe<0><<<1024, 512, 0, stream>>>(Fbf, F, dwF, uwF, db, flatw, biasws, out);
  } else {
    k_moe<1><<<1024, 512, 0, stream>>>(nullptr, F, dwF, uwF, db, flatw, biasws, out);
  }
}

// Round 9
// 1135.280 us; speedup vs baseline: 1.5368x; 1.2650x over previous
//
#include <hip/hip_runtime.h>
#include <math.h>

typedef unsigned int u32;
typedef unsigned short u16;
typedef unsigned char u8;
typedef unsigned long long u64;
typedef float f32x4 __attribute__((ext_vector_type(4)));

#define B_  16
#define S_  2048
#define D_  1024
#define H_  256
#define SD_ 14
#define C_  6
#define G_  3
#define E_  18

// float -> OCP e4m3fn with RNE (no inf; max 448; subnormal step 2^-9)
static __device__ __forceinline__ u8 f2e4m3(float f) {
  u32 u = __builtin_bit_cast(u32, f);
  u8 s = (u8)((u >> 24) & 0x80u);
  float a = __builtin_fabsf(f);
  if (a >= 464.f) return s | 0x7E;
  if (a < 0.015625f) {                       // subnormal (or zero)
    u32 q = (u32)__builtin_rintf(a * 512.f); // 0..8 (8 carries into min normal)
    return s | (u8)q;
  }
  u32 b = __builtin_bit_cast(u32, a);
  b += 0x7FFFFu + ((b >> 20) & 1u);          // RNE to 3 mantissa bits
  u32 exp8 = ((b >> 23) & 0xffu) - 120u;     // rebias 127 -> 7
  u32 man3 = (b >> 20) & 7u;
  return s | (u8)((exp8 << 3) | man3);
}

// ---------------- K3: F f32 -> fp8(x4) + column-mean pooling ----------------
__global__ __launch_bounds__(256) void k_convpool8(const float* __restrict__ F,
                                                   u8* __restrict__ F8,
                                                   float* __restrict__ fsum) {
  const int bb = blockIdx.x >> 5;
  const int sc = blockIdx.x & 31;
  const int t  = threadIdx.x;
  const size_t base = (size_t)(bb * S_ + sc * 64) * D_ + t * 4;
  float s0 = 0.f, s1 = 0.f, s2 = 0.f, s3 = 0.f;
  for (int i = 0; i < 64; ++i) {
    const f32x4 v = *(const f32x4*)(F + base + (size_t)i * D_);
    s0 += v[0]; s1 += v[1]; s2 += v[2]; s3 += v[3];
    u32 q = (u32)f2e4m3(v[0] * 4.f) | ((u32)f2e4m3(v[1] * 4.f) << 8) |
            ((u32)f2e4m3(v[2] * 4.f) << 16) | ((u32)f2e4m3(v[3] * 4.f) << 24);
    *(u32*)(F8 + base + (size_t)i * D_) = q;
  }
  const int c = t * 4;
  atomicAdd(&fsum[bb * D_ + c + 0], s0);
  atomicAdd(&fsum[bb * D_ + c + 1], s1);
  atomicAdd(&fsum[bb * D_ + c + 2], s2);
  atomicAdd(&fsum[bb * D_ + c + 3], s3);
}

// ---------------- K3b: pooling only (lean path) ----------------
__global__ __launch_bounds__(256) void k_poolF(const float* __restrict__ F,
                                               float* __restrict__ fsum) {
  const int bb = blockIdx.x >> 5;
  const int sc = blockIdx.x & 31;
  const int t  = threadIdx.x;
  const size_t base = (size_t)(bb * S_ + sc * 64) * D_ + t * 4;
  float s0 = 0.f, s1 = 0.f, s2 = 0.f, s3 = 0.f;
  for (int i = 0; i < 64; ++i) {
    const f32x4 v = *(const f32x4*)(F + base + (size_t)i * D_);
    s0 += v[0]; s1 += v[1]; s2 += v[2]; s3 += v[3];
  }
  const int c = t * 4;
  atomicAdd(&fsum[bb * D_ + c + 0], s0);
  atomicAdd(&fsum[bb * D_ + c + 1], s1);
  atomicAdd(&fsum[bb * D_ + c + 2], s2);
  atomicAdd(&fsum[bb * D_ + c + 3], s3);
}

// ---------------- K1: x_raw column-mean pooling ----------------
__global__ __launch_bounds__(256) void k_xpool(const float* __restrict__ X,
                                               float* __restrict__ xsum) {
  const int b = blockIdx.x;
  const int t = threadIdx.x;
  float ls[SD_];
  #pragma unroll
  for (int c = 0; c < SD_; ++c) ls[c] = 0.f;
  for (int s = t; s < S_; s += 256) {
    const float* row = X + (size_t)(b * S_ + s) * SD_;
    #pragma unroll
    for (int c = 0; c < SD_; ++c) ls[c] += row[c];
  }
  #pragma unroll
  for (int c = 0; c < SD_; ++c) atomicAdd(&xsum[b * SD_ + c], ls[c]);
}

// ---------------- K2: routers + flat weights + expert loads + lb + bias term ----------------
__global__ __launch_bounds__(256) void k_router(const float* __restrict__ fsum,
                                                const float* __restrict__ xsum,
                                                const float* __restrict__ cond_w,
                                                const float* __restrict__ cond_b,
                                                const float* __restrict__ stage_w,
                                                const float* __restrict__ stage_b,
                                                const float* __restrict__ up_b,
                                                float* __restrict__ flatw,
                                                float* __restrict__ biasws,
                                                float* __restrict__ out_tail) {
  __shared__ float s_cl[B_][C_], s_sl[B_][G_];
  __shared__ float s_cw[B_][C_], s_sw[B_][G_];
  __shared__ float s_fw[B_][E_], s_ld[E_];
  const int t = threadIdx.x;
  if (t < B_ * C_) {
    const int b = t / C_, c = t % C_;
    float a = cond_b[c];
    for (int d = 0; d < D_; ++d) a += (fsum[b * D_ + d] * (1.f / S_)) * cond_w[d * C_ + c];
    s_cl[b][c] = a;
  }
  if (t < B_ * G_) {
    const int b = t / G_, g = t % G_;
    float a = stage_b[g];
    for (int sd = 0; sd < SD_; ++sd) a += (xsum[b * SD_ + sd] * (1.f / S_)) * stage_w[sd * G_ + g];
    s_sl[b][g] = a;
  }
  __syncthreads();
  if (t < B_) {
    float m = s_cl[t][0];
    for (int c = 1; c < C_; ++c) m = fmaxf(m, s_cl[t][c]);
    float den = 0.f, ex[C_];
    for (int c = 0; c < C_; ++c) { ex[c] = expf(s_cl[t][c] - m); den += ex[c]; }
    for (int c = 0; c < C_; ++c) s_cw[t][c] = ex[c] / den;
    float m2 = s_sl[t][0];
    for (int g = 1; g < G_; ++g) m2 = fmaxf(m2, s_sl[t][g]);
    float den2 = 0.f, ex2[G_];
    for (int g = 0; g < G_; ++g) { ex2[g] = expf(s_sl[t][g] - m2); den2 += ex2[g]; }
    for (int g = 0; g < G_; ++g) s_sw[t][g] = ex2[g] / den2;
    for (int c = 0; c < C_; ++c)
      for (int g = 0; g < G_; ++g) s_fw[t][c * G_ + g] = s_cw[t][c] * s_sw[t][g];
  }
  __syncthreads();
  if (t < B_ * C_) out_tail[t] = s_cw[t / C_][t % C_];
  if (t < B_ * G_) out_tail[B_ * C_ + t] = s_sw[t / G_][t % G_];
  for (int i = t; i < B_ * E_; i += 256) flatw[i] = s_fw[i / E_][i % E_];
  if (t < E_) {
    float a = 0.f;
    for (int b = 0; b < B_; ++b) a += s_fw[b][t];
    s_ld[t] = a / (float)B_;
    out_tail[B_ * C_ + B_ * G_ + t] = s_ld[t];
  }
  __syncthreads();
  if (t == 0) {
    float a = 0.f;
    for (int e = 0; e < E_; ++e) a += s_ld[e] * s_ld[e];
    out_tail[B_ * C_ + B_ * G_ + E_] = (float)E_ * a * 0.01f;
  }
  for (int i = t; i < B_ * D_; i += 256) {
    const int b = i >> 10, d = i & 1023;
    float a = 0.f;
    #pragma unroll
    for (int e = 0; e < E_; ++e) a += s_fw[b][e] * up_b[e * D_ + d];
    biasws[i] = a;
  }
}

// ---------------- K4: fragmentizer to fp8 ----------------
// src [E][K][N] f32 -> dst frag-linear e4m3 [e][kb=K/32][cb=N/16][lane=64][8B]:
//   dst byte j of lane l = e4m3(src[e][kb*32 + (l>>4)*8 + j][cb*16 + (l&15)] * scale)
__global__ __launch_bounds__(256) void k_frag8(const float* __restrict__ src,
                                               u8* __restrict__ dst, int K, int N,
                                               float scale) {
  const int kgrp = K >> 7;
  const int ncb = N >> 4;
  const int bid = blockIdx.x;
  const int kbg = bid % kgrp;
  const int cb  = (bid / kgrp) % ncb;
  const int e   = bid / (kgrp * ncb);
  __shared__ float tile[128][17];
  const int t = threadIdx.x;
  #pragma unroll
  for (int it = 0; it < 8; ++it) {
    const int i = it * 256 + t;
    const int row = i >> 4, col = i & 15;
    tile[row][col] = src[((size_t)e * K + kbg * 128 + row) * N + cb * 16 + col];
  }
  __syncthreads();
  const int lane = t & 63, kbq = t >> 6;
  const int l15 = lane & 15, lhi = lane >> 4;
  const int kb = kbg * 4 + kbq;
  u64 v = 0;
  #pragma unroll
  for (int j = 0; j < 8; ++j)
    v |= (u64)f2e4m3(tile[kbq * 32 + lhi * 8 + j][l15] * scale) << (8 * j);
  *(u64*)(dst + ((((size_t)e * (K >> 5) + kb) * ncb + cb) * 64 + lane) * 8) = v;
}

#define MFMA_FP8 __builtin_amdgcn_mfma_f32_16x16x32_fp8_fp8

// fast gelu (tanh form via exp2)
static __device__ __forceinline__ float gelu_f(float x) {
  float y2 = 2.302208f * x * (1.f + 0.044715f * x * x);
  y2 = fminf(fmaxf(y2, -30.f), 30.f);
  const float p = __builtin_exp2f(y2);
  return x * p / (p + 1.f);
}

// ---------------- K5: fused MoE main kernel (v9 = v5 structure, fp8 operands) ----------------
// BM=32, 512 thr / 8 waves, 2 waves/SIMD (256-reg total budget, HW-calibrated).
// fp8 everywhere in the GEMMs: weight bytes HALVE (19.3 GB -> 9.7 GB of L2/L3
// re-reads, the suspected v5 ceiling) and frags are 2 VGPR -> depth-8 down-B
// prefetch at v5's depth-4 cost. Scales: F x4, dw x16 (hacc/64), h x8, uw x16
// (acc/128) keep e4m3 in its normal range; all folded out exactly in f32.
template<int LEAN>
__global__ __launch_bounds__(512, 2) void k_moe(const u8* __restrict__ F8,
                                                const float* __restrict__ Ff32,
                                                const u8* __restrict__ dwF8,   // [e][32][16][64][8B]
                                                const u8* __restrict__ uwF8,   // [e][8][64][64][8B]
                                                const float* __restrict__ down_b,
                                                const float* __restrict__ flatw,
                                                const float* __restrict__ biasws,
                                                float* __restrict__ out) {
  __shared__ u8 Fb[32 * 1024];     // 32 KiB; row=1024B; XOR-swizzle on 8B units
  __shared__ u8 Hb[2][32 * 256];   // 2 x 8 KiB; row=256B; same swizzle

  const int tile = blockIdx.x;
  const int r0 = tile * 32;
  const int b = r0 >> 11;
  const int t = threadIdx.x;
  const int w = t >> 6;
  const int l = t & 63;
  const int l15 = l & 15;
  const int lhi = l >> 4;
  const int r7 = l15 & 7;          // (row & 7) for rows l15 + fr*16

  // ---- stage F tile (fp8), swizzled: lds[row*1024 + ((o8 ^ (row&7))<<3)] ----
  #pragma unroll
  for (int i = 0; i < 8; ++i) {
    const int idx = i * 512 + t;     // 4096 8B-units
    const int row = idx >> 7;        // 0..31
    const int o8  = idx & 127;
    u64 v;
    if constexpr (!LEAN) {
      v = *(const u64*)(F8 + (size_t)(r0 + row) * D_ + o8 * 8);
    } else {
      const float* src = Ff32 + (size_t)(r0 + row) * D_ + o8 * 8;
      v = 0;
      #pragma unroll
      for (int j = 0; j < 8; ++j) v |= (u64)f2e4m3(src[j] * 4.f) << (8 * j);
    }
    *(u64*)(Fb + row * 1024 + (size_t)((o8 ^ (row & 7)) << 3)) = v;
  }

  // per-lane frag bases (frag = 512B, lane l at +l*8)
  const u8* dB = dwF8 + ((size_t)(2 * w) * 64 + l) * 8;  // +((e*32+kk)*16)*512, +512 for cb+1

  // preload expert-0 down-B, depth 8
  long pb[8][2];
  #pragma unroll
  for (int p = 0; p < 8; ++p) {
    pb[p][0] = *(const long*)(dB + (size_t)p * 16 * 512);
    pb[p][1] = *(const long*)(dB + (size_t)p * 16 * 512 + 512);
  }

  f32x4 acc[2][8];
  #pragma unroll
  for (int i = 0; i < 2; ++i)
    #pragma unroll
    for (int j = 0; j < 8; ++j)
      acc[i][j] = f32x4{0.f, 0.f, 0.f, 0.f};

  __syncthreads();

  const float* fwb = flatw + b * E_;

  #pragma unroll 1
  for (int e = 0; e < E_; ++e) {
    u8* hb = Hb[e & 1];
    const u8* dBe = dB + (size_t)e * 32 * 16 * 512;

    // ---- DOWN: h[32 x 32cols/wave] = F(32x1024) @ dw[e], K=1024 ----
    f32x4 hacc[2][2];
    #pragma unroll
    for (int fr = 0; fr < 2; ++fr) {
      hacc[fr][0] = f32x4{0.f, 0.f, 0.f, 0.f};
      hacc[fr][1] = f32x4{0.f, 0.f, 0.f, 0.f};
    }
    long areg[2][2];
    #pragma unroll
    for (int fr = 0; fr < 2; ++fr)
      areg[0][fr] = *(const long*)(Fb + (l15 + fr * 16) * 1024 + (((0 * 4 + lhi) ^ r7) << 3));
    #pragma unroll
    for (int kk = 0; kk < 32; ++kk) {
      const int cur = kk & 1, nxt = cur ^ 1;
      if (kk < 31) {
        const int o8n = (kk + 1) * 4 + lhi;
        #pragma unroll
        for (int fr = 0; fr < 2; ++fr)
          areg[nxt][fr] = *(const long*)(Fb + (l15 + fr * 16) * 1024 + ((o8n ^ r7) << 3));
      }
      const long b0 = pb[kk & 7][0];
      const long b1 = pb[kk & 7][1];
      if (kk < 24) {
        pb[kk & 7][0] = *(const long*)(dBe + (size_t)(kk + 8) * 16 * 512);
        pb[kk & 7][1] = *(const long*)(dBe + (size_t)(kk + 8) * 16 * 512 + 512);
      }
      #pragma unroll
      for (int fr = 0; fr < 2; ++fr) {
        hacc[fr][0] = MFMA_FP8(areg[cur][fr], b0, hacc[fr][0], 0, 0, 0);
        hacc[fr][1] = MFMA_FP8(areg[cur][fr], b1, hacc[fr][1], 0, 0, 0);
      }
    }

    // ---- issue up-B(ks=0) + next-expert pb, then gelu -> Hb[e&1] ----
    const u8* uBe = uwF8 + ((size_t)e * 8 * 64 + 8 * w) * 512 + l * 8;
    long ub[2][8];
    #pragma unroll
    for (int fc = 0; fc < 8; ++fc)
      ub[0][fc] = *(const long*)(uBe + (size_t)fc * 512);

    if (e + 1 < E_) {
      const u8* dBn = dB + (size_t)(e + 1) * 32 * 16 * 512;
      #pragma unroll
      for (int p = 0; p < 8; ++p) {
        pb[p][0] = *(const long*)(dBn + (size_t)p * 16 * 512);
        pb[p][1] = *(const long*)(dBn + (size_t)p * 16 * 512 + 512);
      }
    }

    const float wbe = fwb[e];
    #pragma unroll
    for (int fc = 0; fc < 2; ++fc) {
      const int hc = w * 32 + fc * 16 + l15;
      const float dbv = down_b[e * H_ + hc];
      const float sc8 = 8.f * wbe;
      #pragma unroll
      for (int fr = 0; fr < 2; ++fr) {
        #pragma unroll
        for (int i = 0; i < 4; ++i) {
          const int row = fr * 16 + lhi * 4 + i;
          const float x = hacc[fr][fc][i] * 0.015625f + dbv;   // /64 undoes F(x4)*dw(x16)
          hb[row * 256 + ((((hc >> 3) ^ (row & 7)) << 3) | (hc & 7))] = f2e4m3(gelu_f(x) * sc8);
        }
      }
    }

    // single barrier/expert: publishes Hb[e&1]; up(e) reads it while gelu(e+1)
    // writes the OTHER buffer; up(e+1) gated by barrier(e+1).
    __syncthreads();

    // ---- UP: acc[32 x 128cols/wave] += Hb(32x256) @ uw[e], K=256 ----
    long ua[2][2];
    #pragma unroll
    for (int fr = 0; fr < 2; ++fr)
      ua[0][fr] = *(const long*)(hb + (l15 + fr * 16) * 256 + (((0 * 4 + lhi) ^ r7) << 3));
    #pragma unroll
    for (int ks = 0; ks < 8; ++ks) {
      const int cur = ks & 1, nxt = cur ^ 1;
      if (ks < 7) {
        #pragma unroll
        for (int fc = 0; fc < 8; ++fc)
          ub[nxt][fc] = *(const long*)(uBe + ((size_t)(ks + 1) * 64 + fc) * 512);
        const int o8n = (ks + 1) * 4 + lhi;
        #pragma unroll
        for (int fr = 0; fr < 2; ++fr)
          ua[nxt][fr] = *(const long*)(hb + (l15 + fr * 16) * 256 + ((o8n ^ r7) << 3));
      }
      #pragma unroll
      for (int fc = 0; fc < 8; ++fc) {
        #pragma unroll
        for (int fr = 0; fr < 2; ++fr)
          acc[fr][fc] = MFMA_FP8(ua[cur][fr], ub[cur][fc], acc[fr][fc], 0, 0, 0);
      }
    }
  }

  // ---- epilogue: residual + bias + store; /128 undoes h(x8)*uw(x16) ----
  const float* bias = biasws + b * D_;
  #pragma unroll
  for (int fc = 0; fc < 8; ++fc) {
    const int col = w * 128 + fc * 16 + l15;
    const float bv = bias[col];
    #pragma unroll
    for (int fr = 0; fr < 2; ++fr) {
      #pragma unroll
      for (int i = 0; i < 4; ++i) {
        const int row = fr * 16 + lhi * 4 + i;
        const size_t idx = (size_t)(r0 + row) * D_ + col;
        out[idx] = acc[fr][fc][i] * 0.0078125f + Ff32[idx] + bv;
      }
    }
  }
}

extern "C" void kernel_launch(void* const* d_in, const int* in_sizes, int n_in,
                              void* d_out, int out_size, void* d_ws, size_t ws_size,
                              hipStream_t stream) {
  const float* F  = (const float*)d_in[0];
  const float* X  = (const float*)d_in[1];
  const float* dw = (const float*)d_in[2];
  const float* db = (const float*)d_in[3];
  const float* uw = (const float*)d_in[4];
  const float* ub = (const float*)d_in[5];
  const float* cw = (const float*)d_in[6];
  const float* cb = (const float*)d_in[7];
  const float* sw = (const float*)d_in[8];
  const float* sb = (const float*)d_in[9];
  float* out = (float*)d_out;

  char* ws = (char*)d_ws;
  float* fsum  = (float*)ws;                 // B*D
  float* xsum  = fsum + B_ * D_;             // B*SD
  float* flatw = xsum + B_ * SD_;            // B*E
  float* biasws = flatw + B_ * E_;           // B*D
  size_t off = (size_t)(B_ * D_ + B_ * SD_ + B_ * E_ + B_ * D_) * 4;
  off = (off + 255) & ~(size_t)255;
  u8* dwF8 = (u8*)(ws + off); off += (size_t)E_ * H_ * D_;
  u8* uwF8 = (u8*)(ws + off); off += (size_t)E_ * D_ * H_;
  const size_t need_lean = off;
  u8* F8 = (u8*)(ws + off); off += (size_t)B_ * S_ * D_;
  const size_t need_full = off;

  if (ws_size < need_lean) return;
  const bool lean = ws_size < need_full;

  hipMemsetAsync(d_ws, 0, (size_t)(B_ * D_ + B_ * SD_) * sizeof(float), stream);
  // dw [E][D=K][H=N] x16 ; uw [E][H=K][D=N] x16
  k_frag8<<<E_ * (H_ / 16) * (D_ / 128), 256, 0, stream>>>(dw, dwF8, D_, H_, 16.f);
  k_frag8<<<E_ * (D_ / 16) * (H_ / 128), 256, 0, stream>>>(uw, uwF8, H_, D_, 16.f);
  if (!lean) {
    k_convpool8<<<512, 256, 0, stream>>>(F, F8, fsum);
  } else {
    k_poolF<<<512, 256, 0, stream>>>(F, fsum);
  }
  k_xpool<<<B_, 256, 0, stream>>>(X, xsum);
  k_router<<<1, 256, 0, stream>>>(fsum, xsum, cw, cb, sw, sb, ub, flatw, biasws,
                                  out + (size_t)B_ * S_ * D_);
  if (!lean) {
    k_moe<0><<<1024, 512, 0, stream>>>(F8, F, dwF8, uwF8, db, flatw, biasws, out);
  } else {
    k_moe<1><<<1024, 512, 0, stream>>>(nullptr, F, dwF8, uwF8, db, flatw, biasws, out);
  }
}

// Round 10
// 890.880 us; speedup vs baseline: 1.9584x; 1.2743x over previous
//
#include <hip/hip_runtime.h>
#include <math.h>

typedef unsigned int u32;
typedef unsigned short u16;
typedef unsigned char u8;
typedef unsigned long long u64;
typedef long i64;
typedef float f32x4 __attribute__((ext_vector_type(4)));
typedef float f32x16 __attribute__((ext_vector_type(16)));

#define B_  16
#define S_  2048
#define D_  1024
#define H_  256
#define SD_ 14
#define C_  6
#define G_  3
#define E_  18

// hardware fp8 (OCP e4m3 on gfx950) pack: 2 floats -> bytes 0,1 of result
static __device__ __forceinline__ u32 pk8(float a, float b) {
  return (u32)__builtin_amdgcn_cvt_pk_fp8_f32(a, b, 0, false);
}

// ---------------- K3: F f32 -> fp8(x4) + column-mean pooling ----------------
__global__ __launch_bounds__(256) void k_convpool8(const float* __restrict__ F,
                                                   u8* __restrict__ F8,
                                                   float* __restrict__ fsum) {
  const int bb = blockIdx.x >> 5;
  const int sc = blockIdx.x & 31;
  const int t  = threadIdx.x;
  const size_t base = (size_t)(bb * S_ + sc * 64) * D_ + t * 4;
  float s0 = 0.f, s1 = 0.f, s2 = 0.f, s3 = 0.f;
  for (int i = 0; i < 64; ++i) {
    const f32x4 v = *(const f32x4*)(F + base + (size_t)i * D_);
    s0 += v[0]; s1 += v[1]; s2 += v[2]; s3 += v[3];
    const u32 q = pk8(v[0] * 4.f, v[1] * 4.f) | (pk8(v[2] * 4.f, v[3] * 4.f) << 16);
    *(u32*)(F8 + base + (size_t)i * D_) = q;
  }
  const int c = t * 4;
  atomicAdd(&fsum[bb * D_ + c + 0], s0);
  atomicAdd(&fsum[bb * D_ + c + 1], s1);
  atomicAdd(&fsum[bb * D_ + c + 2], s2);
  atomicAdd(&fsum[bb * D_ + c + 3], s3);
}

// ---------------- K3b: pooling only (lean path) ----------------
__global__ __launch_bounds__(256) void k_poolF(const float* __restrict__ F,
                                               float* __restrict__ fsum) {
  const int bb = blockIdx.x >> 5;
  const int sc = blockIdx.x & 31;
  const int t  = threadIdx.x;
  const size_t base = (size_t)(bb * S_ + sc * 64) * D_ + t * 4;
  float s0 = 0.f, s1 = 0.f, s2 = 0.f, s3 = 0.f;
  for (int i = 0; i < 64; ++i) {
    const f32x4 v = *(const f32x4*)(F + base + (size_t)i * D_);
    s0 += v[0]; s1 += v[1]; s2 += v[2]; s3 += v[3];
  }
  const int c = t * 4;
  atomicAdd(&fsum[bb * D_ + c + 0], s0);
  atomicAdd(&fsum[bb * D_ + c + 1], s1);
  atomicAdd(&fsum[bb * D_ + c + 2], s2);
  atomicAdd(&fsum[bb * D_ + c + 3], s3);
}

// ---------------- K1: x_raw column-mean pooling ----------------
__global__ __launch_bounds__(256) void k_xpool(const float* __restrict__ X,
                                               float* __restrict__ xsum) {
  const int b = blockIdx.x;
  const int t = threadIdx.x;
  float ls[SD_];
  #pragma unroll
  for (int c = 0; c < SD_; ++c) ls[c] = 0.f;
  for (int s = t; s < S_; s += 256) {
    const float* row = X + (size_t)(b * S_ + s) * SD_;
    #pragma unroll
    for (int c = 0; c < SD_; ++c) ls[c] += row[c];
  }
  #pragma unroll
  for (int c = 0; c < SD_; ++c) atomicAdd(&xsum[b * SD_ + c], ls[c]);
}

// ---------------- K2: routers + flat weights + expert loads + lb + bias term ----------------
__global__ __launch_bounds__(256) void k_router(const float* __restrict__ fsum,
                                                const float* __restrict__ xsum,
                                                const float* __restrict__ cond_w,
                                                const float* __restrict__ cond_b,
                                                const float* __restrict__ stage_w,
                                                const float* __restrict__ stage_b,
                                                const float* __restrict__ up_b,
                                                float* __restrict__ flatw,
                                                float* __restrict__ biasws,
                                                float* __restrict__ out_tail) {
  __shared__ float s_cl[B_][C_], s_sl[B_][G_];
  __shared__ float s_cw[B_][C_], s_sw[B_][G_];
  __shared__ float s_fw[B_][E_], s_ld[E_];
  const int t = threadIdx.x;
  if (t < B_ * C_) {
    const int b = t / C_, c = t % C_;
    float a = cond_b[c];
    for (int d = 0; d < D_; ++d) a += (fsum[b * D_ + d] * (1.f / S_)) * cond_w[d * C_ + c];
    s_cl[b][c] = a;
  }
  if (t < B_ * G_) {
    const int b = t / G_, g = t % G_;
    float a = stage_b[g];
    for (int sd = 0; sd < SD_; ++sd) a += (xsum[b * SD_ + sd] * (1.f / S_)) * stage_w[sd * G_ + g];
    s_sl[b][g] = a;
  }
  __syncthreads();
  if (t < B_) {
    float m = s_cl[t][0];
    for (int c = 1; c < C_; ++c) m = fmaxf(m, s_cl[t][c]);
    float den = 0.f, ex[C_];
    for (int c = 0; c < C_; ++c) { ex[c] = expf(s_cl[t][c] - m); den += ex[c]; }
    for (int c = 0; c < C_; ++c) s_cw[t][c] = ex[c] / den;
    float m2 = s_sl[t][0];
    for (int g = 1; g < G_; ++g) m2 = fmaxf(m2, s_sl[t][g]);
    float den2 = 0.f, ex2[G_];
    for (int g = 0; g < G_; ++g) { ex2[g] = expf(s_sl[t][g] - m2); den2 += ex2[g]; }
    for (int g = 0; g < G_; ++g) s_sw[t][g] = ex2[g] / den2;
    for (int c = 0; c < C_; ++c)
      for (int g = 0; g < G_; ++g) s_fw[t][c * G_ + g] = s_cw[t][c] * s_sw[t][g];
  }
  __syncthreads();
  if (t < B_ * C_) out_tail[t] = s_cw[t / C_][t % C_];
  if (t < B_ * G_) out_tail[B_ * C_ + t] = s_sw[t / G_][t % G_];
  for (int i = t; i < B_ * E_; i += 256) flatw[i] = s_fw[i / E_][i % E_];
  if (t < E_) {
    float a = 0.f;
    for (int b = 0; b < B_; ++b) a += s_fw[b][t];
    s_ld[t] = a / (float)B_;
    out_tail[B_ * C_ + B_ * G_ + t] = s_ld[t];
  }
  __syncthreads();
  if (t == 0) {
    float a = 0.f;
    for (int e = 0; e < E_; ++e) a += s_ld[e] * s_ld[e];
    out_tail[B_ * C_ + B_ * G_ + E_] = (float)E_ * a * 0.01f;
  }
  for (int i = t; i < B_ * D_; i += 256) {
    const int b = i >> 10, d = i & 1023;
    float a = 0.f;
    #pragma unroll
    for (int e = 0; e < E_; ++e) a += s_fw[b][e] * up_b[e * D_ + d];
    biasws[i] = a;
  }
}

// ---------------- K4: fragmentizer to fp8 for 32x32x16 MFMA ----------------
// src [E][K][N] f32 -> dst frag-linear e4m3 [e][kb=K/16][cb=N/32][lane=64][8B]:
//   byte j of lane l = e4m3(src[e][kb*16 + (l>>5)*8 + j][cb*32 + (l&31)] * scale)
__global__ __launch_bounds__(256) void k_frag8(const float* __restrict__ src,
                                               u8* __restrict__ dst, int K, int N,
                                               float scale) {
  const int kgrp = K >> 7;           // 128 k-rows per block
  const int ncb = N >> 5;
  const int bid = blockIdx.x;
  const int kbg = bid % kgrp;
  const int cb  = (bid / kgrp) % ncb;
  const int e   = bid / (kgrp * ncb);
  __shared__ float tile[128][33];
  const int t = threadIdx.x;
  #pragma unroll
  for (int it = 0; it < 16; ++it) {
    const int i = it * 256 + t;
    const int row = i >> 5, col = i & 31;
    tile[row][col] = src[((size_t)e * K + kbg * 128 + row) * N + cb * 32 + col];
  }
  __syncthreads();
  const int lane = t & 63, q = t >> 6;     // q = 0..3
  const int l31 = lane & 31, lhi = lane >> 5;
  #pragma unroll
  for (int h2 = 0; h2 < 2; ++h2) {
    const int kbq = q * 2 + h2;            // 0..7
    const int kb = kbg * 8 + kbq;
    float x[8];
    #pragma unroll
    for (int j = 0; j < 8; ++j) x[j] = tile[kbq * 16 + lhi * 8 + j][l31] * scale;
    const u32 lo = pk8(x[0], x[1]) | (pk8(x[2], x[3]) << 16);
    const u32 hi = pk8(x[4], x[5]) | (pk8(x[6], x[7]) << 16);
    *(u64*)(dst + ((((size_t)e * (K >> 4) + kb) * ncb + cb) * 64 + lane) * 8) =
        (u64)lo | ((u64)hi << 32);
  }
}

#define MFMA32 __builtin_amdgcn_mfma_f32_32x32x16_fp8_fp8

// fast gelu (tanh form via exp2)
static __device__ __forceinline__ float gelu_f(float x) {
  float y2 = 2.302208f * x * (1.f + 0.044715f * x * x);
  y2 = fminf(fmaxf(y2, -30.f), 30.f);
  const float p = __builtin_exp2f(y2);
  return x * p / (p + 1.f);
}

// ---------------- K5: fused MoE main kernel (v10 = v9 structure, 32x32x16 MFMA) ----------------
// BM=32, 512 thr / 8 waves, 2 waves/SIMD (256-reg total budget, HW-calibrated).
// 32x32x16 fp8 MFMA: 2x FLOP/instr -> MFMA instrs, frag loads, LDS reads all
// HALVE vs v9; per-instruction stalls (the ~70% non-pipe time at v9's
// MfmaUtil=26%) amortize over 2x the work. Down uses 2 interleaved acc chains.
// A/B frag: row|col = l&31, k = (l>>5)*8+j. C/D: col=l&31,
// row=(reg&3)+8*(reg>>2)+4*(l>>5). Swizzle: XOR (row&15) on 8B units.
template<int LEAN>
__global__ __launch_bounds__(512, 2) void k_moe(const u8* __restrict__ F8,
                                                const float* __restrict__ Ff32,
                                                const u8* __restrict__ dwF8,   // [e][64][8][64][8B]
                                                const u8* __restrict__ uwF8,   // [e][16][32][64][8B]
                                                const float* __restrict__ down_b,
                                                const float* __restrict__ flatw,
                                                const float* __restrict__ biasws,
                                                float* __restrict__ out) {
  __shared__ u8 Fb[32 * 1024];     // 32 KiB; row=1024B; XOR-swizzle (row&15) on 8B units
  __shared__ u8 Hb[2][32 * 256];   // 2 x 8 KiB; row=256B; same swizzle

  const int tile = blockIdx.x;
  const int r0 = tile * 32;
  const int b = r0 >> 11;
  const int t = threadIdx.x;
  const int w = t >> 6;
  const int l = t & 63;
  const int l31 = l & 31;
  const int lhi = l >> 5;          // 0..1
  const int r15 = l31 & 15;        // (row & 15) for row = l31

  // ---- stage F tile (fp8, swizzled) ----
  #pragma unroll
  for (int i = 0; i < 8; ++i) {
    const int idx = i * 512 + t;     // 4096 8B-units
    const int row = idx >> 7;        // 0..31
    const int o8  = idx & 127;
    u64 v;
    if constexpr (!LEAN) {
      v = *(const u64*)(F8 + (size_t)(r0 + row) * D_ + o8 * 8);
    } else {
      const float* src = Ff32 + (size_t)(r0 + row) * D_ + o8 * 8;
      const u32 lo = pk8(src[0] * 4.f, src[1] * 4.f) | (pk8(src[2] * 4.f, src[3] * 4.f) << 16);
      const u32 hi = pk8(src[4] * 4.f, src[5] * 4.f) | (pk8(src[6] * 4.f, src[7] * 4.f) << 16);
      v = (u64)lo | ((u64)hi << 32);
    }
    *(u64*)(Fb + row * 1024 + (size_t)((o8 ^ (row & 15)) << 3)) = v;
  }

  // down-B frag base: [e][kb][cb=w][lane][8B]; per kb stride = 8*512B
  const u8* dB = dwF8 + ((size_t)w * 64 + l) * 8;

  // preload expert-0 down-B, depth 8 (kb=0..7) — 16 VGPRs
  i64 pb[8];
  #pragma unroll
  for (int p = 0; p < 8; ++p)
    pb[p] = *(const i64*)(dB + (size_t)p * 8 * 512);

  f32x16 acc[4];
  #pragma unroll
  for (int j = 0; j < 4; ++j)
    #pragma unroll
    for (int i = 0; i < 16; ++i) acc[j][i] = 0.f;

  __syncthreads();

  const float* fwb = flatw + b * E_;

  #pragma unroll 1
  for (int e = 0; e < E_; ++e) {
    u8* hb = Hb[e & 1];
    const u8* dBe = dB + (size_t)e * 64 * 8 * 512;

    // ---- DOWN: h[32 x 32cols/wave] = F(32x1024) @ dw[e], 64 k-steps ----
    f32x16 hacc0, hacc1;   // even/odd-k chains
    #pragma unroll
    for (int i = 0; i < 16; ++i) { hacc0[i] = 0.f; hacc1[i] = 0.f; }
    i64 areg[2];
    areg[0] = *(const i64*)(Fb + l31 * 1024 + (((0 * 2 + lhi) ^ r15) << 3));
    #pragma unroll
    for (int kk = 0; kk < 64; ++kk) {
      const int cur = kk & 1, nxt = cur ^ 1;
      if (kk < 63) {
        const int o8n = (kk + 1) * 2 + lhi;
        areg[nxt] = *(const i64*)(Fb + l31 * 1024 + ((o8n ^ r15) << 3));
      }
      const i64 bb = pb[kk & 7];
      if (kk < 56)
        pb[kk & 7] = *(const i64*)(dBe + (size_t)(kk + 8) * 8 * 512);
      if (cur == 0) hacc0 = MFMA32(areg[cur], bb, hacc0, 0, 0, 0);
      else          hacc1 = MFMA32(areg[cur], bb, hacc1, 0, 0, 0);
    }

    // ---- issue up-B(ks=0) + next-expert pb, then gelu -> Hb[e&1] ----
    const u8* uBe = uwF8 + ((size_t)e * 16 * 32 + (size_t)w * 4) * 512 + l * 8;
    i64 ub[2][4];
    #pragma unroll
    for (int fc = 0; fc < 4; ++fc)
      ub[0][fc] = *(const i64*)(uBe + (size_t)fc * 512);

    if (e + 1 < E_) {
      const u8* dBn = dB + (size_t)(e + 1) * 64 * 8 * 512;
      #pragma unroll
      for (int p = 0; p < 8; ++p)
        pb[p] = *(const i64*)(dBn + (size_t)p * 8 * 512);
    }

    const float wbe = fwb[e];
    {
      const int hc = w * 32 + l31;               // this lane's h-col
      const float dbv = down_b[e * H_ + hc];
      const float sc8 = 8.f * wbe;
      const int cswz_hi = hc & 7;                // low byte bits within 8B unit
      const int co8 = hc >> 3;                   // 8B unit of col
      #pragma unroll
      for (int q = 0; q < 4; ++q) {              // reg quads: rows 8q + {0..3} + 4*lhi
        float g[4];
        #pragma unroll
        for (int j = 0; j < 4; ++j) {
          const float x = (hacc0[q * 4 + j] + hacc1[q * 4 + j]) * 0.015625f + dbv;
          g[j] = gelu_f(x) * sc8;
        }
        const u32 p01 = pk8(g[0], g[1]);
        const u32 p23 = pk8(g[2], g[3]);
        #pragma unroll
        for (int j = 0; j < 4; ++j) {
          const int row = 8 * q + j + 4 * lhi;
          const u8 byte = (u8)((j < 2 ? p01 : p23) >> (8 * (j & 1)));
          hb[row * 256 + (((co8 ^ (row & 15)) << 3) | cswz_hi)] = byte;
        }
      }
    }

    // single barrier/expert: publishes Hb[e&1]; up(e) reads it while gelu(e+1)
    // writes the OTHER buffer; up(e+1) gated by barrier(e+1).
    __syncthreads();

    // ---- UP: acc[32 x 128cols/wave] += Hb(32x256) @ uw[e], 16 k-steps ----
    i64 ua[2];
    ua[0] = *(const i64*)(hb + l31 * 256 + (((0 * 2 + lhi) ^ r15) << 3));
    #pragma unroll
    for (int ks = 0; ks < 16; ++ks) {
      const int cur = ks & 1, nxt = cur ^ 1;
      if (ks < 15) {
        #pragma unroll
        for (int fc = 0; fc < 4; ++fc)
          ub[nxt][fc] = *(const i64*)(uBe + ((size_t)(ks + 1) * 32 + fc) * 512);
        const int o8n = (ks + 1) * 2 + lhi;
        ua[nxt] = *(const i64*)(hb + l31 * 256 + ((o8n ^ r15) << 3));
      }
      #pragma unroll
      for (int fc = 0; fc < 4; ++fc)
        acc[fc] = MFMA32(ua[cur], ub[cur][fc], acc[fc], 0, 0, 0);
    }
  }

  // ---- epilogue: residual + bias + store; /128 undoes h(x8)*uw(x16) ----
  const float* bias = biasws + b * D_;
  #pragma unroll
  for (int fc = 0; fc < 4; ++fc) {
    const int col = w * 128 + fc * 32 + l31;
    const float bv = bias[col];
    #pragma unroll
    for (int r = 0; r < 16; ++r) {
      const int row = (r & 3) + 8 * (r >> 2) + 4 * lhi;
      const size_t idx = (size_t)(r0 + row) * D_ + col;
      out[idx] = acc[fc][r] * 0.0078125f + Ff32[idx] + bv;
    }
  }
}

extern "C" void kernel_launch(void* const* d_in, const int* in_sizes, int n_in,
                              void* d_out, int out_size, void* d_ws, size_t ws_size,
                              hipStream_t stream) {
  const float* F  = (const float*)d_in[0];
  const float* X  = (const float*)d_in[1];
  const float* dw = (const float*)d_in[2];
  const float* db = (const float*)d_in[3];
  const float* uw = (const float*)d_in[4];
  const float* ub = (const float*)d_in[5];
  const float* cw = (const float*)d_in[6];
  const float* cb = (const float*)d_in[7];
  const float* sw = (const float*)d_in[8];
  const float* sb = (const float*)d_in[9];
  float* out = (float*)d_out;

  char* ws = (char*)d_ws;
  float* fsum  = (float*)ws;                 // B*D
  float* xsum  = fsum + B_ * D_;             // B*SD
  float* flatw = xsum + B_ * SD_;            // B*E
  float* biasws = flatw + B_ * E_;           // B*D
  size_t off = (size_t)(B_ * D_ + B_ * SD_ + B_ * E_ + B_ * D_) * 4;
  off = (off + 255) & ~(size_t)255;
  u8* dwF8 = (u8*)(ws + off); off += (size_t)E_ * H_ * D_;
  u8* uwF8 = (u8*)(ws + off); off += (size_t)E_ * D_ * H_;
  const size_t need_lean = off;
  u8* F8 = (u8*)(ws + off); off += (size_t)B_ * S_ * D_;
  const size_t need_full = off;

  if (ws_size < need_lean) return;
  const bool lean = ws_size < need_full;

  hipMemsetAsync(d_ws, 0, (size_t)(B_ * D_ + B_ * SD_) * sizeof(float), stream);
  // dw [E][D=K][H=N] x16 ; uw [E][H=K][D=N] x16  (32x32x16 frag layout)
  k_frag8<<<E_ * (D_ / 128) * (H_ / 32), 256, 0, stream>>>(dw, dwF8, D_, H_, 16.f);
  k_frag8<<<E_ * (H_ / 128) * (D_ / 32), 256, 0, stream>>>(uw, uwF8, H_, D_, 16.f);
  if (!lean) {
    k_convpool8<<<512, 256, 0, stream>>>(F, F8, fsum);
  } else {
    k_poolF<<<512, 256, 0, stream>>>(F, fsum);
  }
  k_xpool<<<B_, 256, 0, stream>>>(X, xsum);
  k_router<<<1, 256, 0, stream>>>(fsum, xsum, cw, cb, sw, sb, ub, flatw, biasws,
                                  out + (size_t)B_ * S_ * D_);
  if (!lean) {
    k_moe<0><<<1024, 512, 0, stream>>>(F8, F, dwF8, uwF8, db, flatw, biasws, out);
  } else {
    k_moe<1><<<1024, 512, 0, stream>>>(nullptr, F, dwF8, uwF8, db, flatw, biasws, out);
  }
}